// Round 7
// baseline (1264.947 us; speedup 1.0000x reference)
//
#include <hip/hip_runtime.h>

#define NUM_USERS 100000
#define NUM_ITEMS 50000
#define NUM_EDGES 4000000
#define DIM 64

// Source-table slicing: 1<<14 = 16384 rows/slice = 2 MB bf16 per slice.
#define SLICE_SHIFT 14
#define SLICES_U ((NUM_USERS + (1 << SLICE_SHIFT) - 1) >> SLICE_SHIFT)  // 7
#define SLICES_I ((NUM_ITEMS + (1 << SLICE_SHIFT) - 1) >> SLICE_SHIFT)  // 4

#define SCAN_NB 512        // blocks in multi-block scan
#define SCAN_THREADS 256

// Packed CSR record: (src_row << 15) | w_quant15.  src_row < 2^17,
// w = edge_norm in [0,1) quantized to 15 bits (err <= 1.5e-5 << bf16 noise).
// ONE scattered 4B store per edge per direction (round-3/6 evidence: scatter
// cost ~ line touches; fewer narrow stores beat fewer-but-wider).
#define W_SCALE 32767.0f
#define W_INV   (1.0f / 32767.0f)

// ---------------- fallback: scatter-atomic (round-1 kernel) ----------------
__global__ __launch_bounds__(256) void lightgcn_scatter(
    const float* __restrict__ user_emb,
    const float* __restrict__ item_emb,
    const float* __restrict__ edge_norm,
    const int* __restrict__ u_idx,
    const int* __restrict__ i_idx,
    float* __restrict__ agg_users,
    float* __restrict__ agg_items)
{
    long long gid = (long long)blockIdx.x * blockDim.x + threadIdx.x;
    int edge = (int)(gid >> 6);
    int lane = (int)(gid & 63);
    if (edge >= NUM_EDGES) return;
    int u = u_idx[edge];
    int i = i_idx[edge];
    float n = edge_norm[edge];
    float uval = user_emb[(size_t)u * DIM + lane];
    float ival = item_emb[(size_t)i * DIM + lane];
    atomicAdd(&agg_items[(size_t)i * DIM + lane], n * uval);
    atomicAdd(&agg_users[(size_t)u * DIM + lane], n * ival);
}

// ---------------- bf16 conversion of embedding tables ----------------
__global__ __launch_bounds__(256) void convert_bf16(
    const float4* __restrict__ src, ushort* __restrict__ dst, int n4)
{
    int t = blockIdx.x * blockDim.x + threadIdx.x;
    if (t >= n4) return;
    float4 v = src[t];
    ushort4 o;
    uint b;
    b = __float_as_uint(v.x); o.x = (ushort)((b + 0x7FFFu + ((b >> 16) & 1u)) >> 16);
    b = __float_as_uint(v.y); o.y = (ushort)((b + 0x7FFFu + ((b >> 16) & 1u)) >> 16);
    b = __float_as_uint(v.z); o.z = (ushort)((b + 0x7FFFu + ((b >> 16) & 1u)) >> 16);
    b = __float_as_uint(v.w); o.w = (ushort)((b + 0x7FFFu + ((b >> 16) & 1u)) >> 16);
    ((ushort4*)dst)[t] = o;
}

// ---------------- CSR build (concatenated bins) ----------------------------
// item bins: [0, n_i) keyed (u_slice, i);  user bins: [n_i, n_i+n_u) keyed
// (i_slice, u). One scan serves both.
__global__ __launch_bounds__(256) void edge_hist(
    const int4* __restrict__ u4, const int4* __restrict__ i4,
    int* __restrict__ cnt, int n_i, int su_shift, int si_shift)
{
    int t = blockIdx.x * blockDim.x + threadIdx.x;
    if (t >= NUM_EDGES / 4) return;
    int4 u = u4[t];
    int4 i = i4[t];
    atomicAdd(&cnt[(u.x >> su_shift) * NUM_ITEMS + i.x], 1);
    atomicAdd(&cnt[(u.y >> su_shift) * NUM_ITEMS + i.y], 1);
    atomicAdd(&cnt[(u.z >> su_shift) * NUM_ITEMS + i.z], 1);
    atomicAdd(&cnt[(u.w >> su_shift) * NUM_ITEMS + i.w], 1);
    atomicAdd(&cnt[n_i + (i.x >> si_shift) * NUM_USERS + u.x], 1);
    atomicAdd(&cnt[n_i + (i.y >> si_shift) * NUM_USERS + u.y], 1);
    atomicAdd(&cnt[n_i + (i.z >> si_shift) * NUM_USERS + u.z], 1);
    atomicAdd(&cnt[n_i + (i.w >> si_shift) * NUM_USERS + u.w], 1);
}

// ---------------- 3-phase multi-block exclusive scan ----------------------
__global__ __launch_bounds__(SCAN_THREADS) void scan_block_sums(
    const int* __restrict__ cnt, int* __restrict__ bsum, int n, int chunk)
{
    int b = blockIdx.x, t = threadIdx.x;
    int base = b * chunk;
    int end  = base + chunk < n ? base + chunk : n;
    int tch  = (chunk + SCAN_THREADS - 1) / SCAN_THREADS;
    int s = base + t * tch;
    int e = s + tch < end ? s + tch : end;
    int local = 0;
    for (int i = s; i < e; ++i) local += cnt[i];
    __shared__ int sm[SCAN_THREADS];
    sm[t] = local;
    __syncthreads();
    for (int o = SCAN_THREADS / 2; o > 0; o >>= 1) {
        if (t < o) sm[t] += sm[t + o];
        __syncthreads();
    }
    if (t == 0) bsum[b] = sm[0];
}

__global__ __launch_bounds__(SCAN_NB) void scan_block_offsets(
    const int* __restrict__ bsum, int* __restrict__ boff,
    int* __restrict__ off_end)
{
    int t = threadIdx.x;
    __shared__ int sm[SCAN_NB];
    int v = bsum[t];
    sm[t] = v;
    __syncthreads();
    for (int o = 1; o < SCAN_NB; o <<= 1) {
        int x = (t >= o) ? sm[t - o] : 0;
        __syncthreads();
        sm[t] += x;
        __syncthreads();
    }
    boff[t] = sm[t] - v;          // exclusive
    if (t == SCAN_NB - 1) *off_end = sm[SCAN_NB - 1];
}

__global__ __launch_bounds__(SCAN_THREADS) void scan_local(
    int* __restrict__ cnt, int* __restrict__ cur,
    const int* __restrict__ boff, int n, int chunk)
{
    int b = blockIdx.x, t = threadIdx.x;
    int base = b * chunk;
    int end  = base + chunk < n ? base + chunk : n;
    int tch  = (chunk + SCAN_THREADS - 1) / SCAN_THREADS;
    int s = base + t * tch;
    int e = s + tch < end ? s + tch : end;
    int local = 0;
    for (int i = s; i < e; ++i) local += cnt[i];
    __shared__ int sm[SCAN_THREADS];
    sm[t] = local;
    __syncthreads();
    for (int o = 1; o < SCAN_THREADS; o <<= 1) {
        int x = (t >= o) ? sm[t - o] : 0;
        __syncthreads();
        sm[t] += x;
        __syncthreads();
    }
    int run = boff[b] + ((t == 0) ? 0 : sm[t - 1]);
    for (int i = s; i < e; ++i) {
        int c = cnt[i];
        cnt[i] = run;
        cur[i] = run;
        run += c;
    }
}

// Placement: ONE packed 4B scattered store per edge per direction.
__global__ __launch_bounds__(256) void edge_place(
    const int* __restrict__ u_idx, const int* __restrict__ i_idx,
    const float* __restrict__ edge_norm,
    int* __restrict__ cur, int n_i,
    uint* __restrict__ rec,
    int su_shift, int si_shift)
{
    int e = blockIdx.x * blockDim.x + threadIdx.x;
    if (e >= NUM_EDGES) return;
    int u = u_idx[e];
    int i = i_idx[e];
    float wt = edge_norm[e];
    uint wq = (uint)(wt * W_SCALE + 0.5f);
    if (wq > 32767u) wq = 32767u;
    int pi = atomicAdd(&cur[(u >> su_shift) * NUM_ITEMS + i], 1);
    rec[pi] = ((uint)u << 15) | wq;
    int pu = atomicAdd(&cur[n_i + (i >> si_shift) * NUM_USERS + u], 1);
    rec[pu] = ((uint)i << 15) | wq;
}

// ---------------- gather pass: one 64-lane wave per dst row, one src slice --
__global__ __launch_bounds__(256) void gather_pass(
    const int* __restrict__ off, int bin_base,
    const uint* __restrict__ rec,
    const ushort* __restrict__ emb16,
    float* __restrict__ out, int nrows, int accumulate)
{
    int gid  = blockIdx.x * blockDim.x + threadIdx.x;
    int row  = gid >> 6;
    int lane = gid & 63;
    if (row >= nrows) return;
    int b = bin_base + row;
    int s = off[b];
    int e = off[b + 1];
    float acc = accumulate ? out[(size_t)row * DIM + lane] : 0.f;
    int k = s;
    for (; k + 8 <= e; k += 8) {
        uint r0 = rec[k],   r1 = rec[k+1], r2 = rec[k+2], r3 = rec[k+3];
        uint r4 = rec[k+4], r5 = rec[k+5], r6 = rec[k+6], r7 = rec[k+7];
        ushort b0 = emb16[(size_t)(r0 >> 15) * DIM + lane];
        ushort b1 = emb16[(size_t)(r1 >> 15) * DIM + lane];
        ushort b2 = emb16[(size_t)(r2 >> 15) * DIM + lane];
        ushort b3 = emb16[(size_t)(r3 >> 15) * DIM + lane];
        ushort b4 = emb16[(size_t)(r4 >> 15) * DIM + lane];
        ushort b5 = emb16[(size_t)(r5 >> 15) * DIM + lane];
        ushort b6 = emb16[(size_t)(r6 >> 15) * DIM + lane];
        ushort b7 = emb16[(size_t)(r7 >> 15) * DIM + lane];
        acc += (float)(r0 & 0x7FFFu) * W_INV * __uint_as_float((uint)b0 << 16);
        acc += (float)(r1 & 0x7FFFu) * W_INV * __uint_as_float((uint)b1 << 16);
        acc += (float)(r2 & 0x7FFFu) * W_INV * __uint_as_float((uint)b2 << 16);
        acc += (float)(r3 & 0x7FFFu) * W_INV * __uint_as_float((uint)b3 << 16);
        acc += (float)(r4 & 0x7FFFu) * W_INV * __uint_as_float((uint)b4 << 16);
        acc += (float)(r5 & 0x7FFFu) * W_INV * __uint_as_float((uint)b5 << 16);
        acc += (float)(r6 & 0x7FFFu) * W_INV * __uint_as_float((uint)b6 << 16);
        acc += (float)(r7 & 0x7FFFu) * W_INV * __uint_as_float((uint)b7 << 16);
    }
    for (; k + 4 <= e; k += 4) {
        uint r0 = rec[k], r1 = rec[k+1], r2 = rec[k+2], r3 = rec[k+3];
        ushort b0 = emb16[(size_t)(r0 >> 15) * DIM + lane];
        ushort b1 = emb16[(size_t)(r1 >> 15) * DIM + lane];
        ushort b2 = emb16[(size_t)(r2 >> 15) * DIM + lane];
        ushort b3 = emb16[(size_t)(r3 >> 15) * DIM + lane];
        acc += (float)(r0 & 0x7FFFu) * W_INV * __uint_as_float((uint)b0 << 16);
        acc += (float)(r1 & 0x7FFFu) * W_INV * __uint_as_float((uint)b1 << 16);
        acc += (float)(r2 & 0x7FFFu) * W_INV * __uint_as_float((uint)b2 << 16);
        acc += (float)(r3 & 0x7FFFu) * W_INV * __uint_as_float((uint)b3 << 16);
    }
    for (; k < e; ++k) {
        uint r0 = rec[k];
        ushort b0 = emb16[(size_t)(r0 >> 15) * DIM + lane];
        acc += (float)(r0 & 0x7FFFu) * W_INV * __uint_as_float((uint)b0 << 16);
    }
    out[(size_t)row * DIM + lane] = acc;
}

extern "C" void kernel_launch(void* const* d_in, const int* in_sizes, int n_in,
                              void* d_out, int out_size, void* d_ws, size_t ws_size,
                              hipStream_t stream) {
    const float* user_emb  = (const float*)d_in[0];
    const float* item_emb  = (const float*)d_in[1];
    const float* edge_norm = (const float*)d_in[2];
    const int*   u_idx     = (const int*)d_in[3];
    const int*   i_idx     = (const int*)d_in[4];

    float* agg_users = (float*)d_out;                        // 100000*64
    float* agg_items = agg_users + (size_t)NUM_USERS * DIM;  // 50000*64

    const size_t csr_bytes  = (size_t)2 * NUM_EDGES * sizeof(uint);
    const size_t bf16_bytes = ((size_t)NUM_USERS + NUM_ITEMS) * DIM * sizeof(ushort);
    auto need_for = [&](int SU, int SI) -> size_t {
        size_t n_total = (size_t)SU * NUM_ITEMS + (size_t)SI * NUM_USERS;
        size_t off_bytes = (2 * n_total + 1 + 2 * SCAN_NB) * sizeof(int);
        return off_bytes + 64 + csr_bytes + 64 + bf16_bytes;
    };

    int SU, SI, su_shift, si_shift;
    if (ws_size >= need_for(SLICES_U, SLICES_I)) {
        SU = SLICES_U; SI = SLICES_I;
        su_shift = SLICE_SHIFT; si_shift = SLICE_SHIFT;
    } else if (ws_size >= need_for(1, 1)) {
        SU = 1; SI = 1;
        su_shift = 17; si_shift = 17;   // 2^17 > both table sizes -> slice 0
    } else {
        hipMemsetAsync(d_out, 0, (size_t)out_size * sizeof(float), stream);
        const long long total_threads = (long long)NUM_EDGES * 64;
        const int blocks = (int)((total_threads + 255) / 256);
        lightgcn_scatter<<<blocks, 256, 0, stream>>>(
            user_emb, item_emb, edge_norm, u_idx, i_idx, agg_users, agg_items);
        return;
    }

    const int n_i = SU * NUM_ITEMS;
    const int n_u = SI * NUM_USERS;
    const int n_total = n_i + n_u;

    char* p = (char*)d_ws;
    int*   cnt  = (int*)p;   p += (size_t)(n_total + 1) * sizeof(int);
    int*   cur  = (int*)p;   p += (size_t)n_total * sizeof(int);
    int*   bsum = (int*)p;   p += (size_t)SCAN_NB * sizeof(int);
    int*   boff = (int*)p;   p += (size_t)SCAN_NB * sizeof(int);
    p = (char*)(((uintptr_t)p + 63) & ~(uintptr_t)63);
    uint*  rec  = (uint*)p;  p += (size_t)2 * NUM_EDGES * sizeof(uint);
    p = (char*)(((uintptr_t)p + 63) & ~(uintptr_t)63);
    ushort* ue16 = (ushort*)p; p += (size_t)NUM_USERS * DIM * sizeof(ushort);
    ushort* ie16 = (ushort*)p;

    // zero the histogram bins (cur is fully written by scan_local)
    hipMemsetAsync(cnt, 0, (size_t)(n_total + 1) * sizeof(int), stream);

    const int un4 = NUM_USERS * DIM / 4;
    const int in4 = NUM_ITEMS * DIM / 4;
    convert_bf16<<<(un4 + 255) / 256, 256, 0, stream>>>(
        (const float4*)user_emb, ue16, un4);
    convert_bf16<<<(in4 + 255) / 256, 256, 0, stream>>>(
        (const float4*)item_emb, ie16, in4);

    edge_hist<<<(NUM_EDGES / 4 + 255) / 256, 256, 0, stream>>>(
        (const int4*)u_idx, (const int4*)i_idx, cnt, n_i, su_shift, si_shift);

    const int chunk = (n_total + SCAN_NB - 1) / SCAN_NB;
    scan_block_sums<<<SCAN_NB, SCAN_THREADS, 0, stream>>>(cnt, bsum, n_total, chunk);
    scan_block_offsets<<<1, SCAN_NB, 0, stream>>>(bsum, boff, cnt + n_total);
    scan_local<<<SCAN_NB, SCAN_THREADS, 0, stream>>>(cnt, cur, boff, n_total, chunk);

    edge_place<<<(NUM_EDGES + 255) / 256, 256, 0, stream>>>(
        u_idx, i_idx, edge_norm, cur, n_i, rec, su_shift, si_shift);

    // agg_items: gather user rows, one launch per user-table slice
    for (int s = 0; s < SU; ++s) {
        gather_pass<<<((NUM_ITEMS * 64) + 255) / 256, 256, 0, stream>>>(
            cnt, s * NUM_ITEMS, rec, ue16, agg_items, NUM_ITEMS, s > 0 ? 1 : 0);
    }
    // agg_users: gather item rows, one launch per item-table slice
    for (int s = 0; s < SI; ++s) {
        gather_pass<<<((NUM_USERS * 64) + 255) / 256, 256, 0, stream>>>(
            cnt, n_i + s * NUM_USERS, rec, ie16, agg_users, NUM_USERS,
            s > 0 ? 1 : 0);
    }
}

// Round 8
// 1146.752 us; speedup vs baseline: 1.1031x; 1.1031x over previous
//
#include <hip/hip_runtime.h>

#define NUM_USERS 100000
#define NUM_ITEMS 50000
#define NUM_EDGES 4000000
#define DIM 64

// Source-table slicing: 1<<14 = 16384 rows/slice = 2 MB bf16 per slice.
#define SLICE_SHIFT 14
#define SLICES_U ((NUM_USERS + (1 << SLICE_SHIFT) - 1) >> SLICE_SHIFT)  // 7
#define SLICES_I ((NUM_ITEMS + (1 << SLICE_SHIFT) - 1) >> SLICE_SHIFT)  // 4

#define SCAN_NB 512
#define SCAN_THREADS 256

// Packed CSR record: (src_row << 15) | w_quant15 (err <= 1.5e-5 << bf16 noise).
#define W_SCALE 32767.0f
#define W_INV   (1.0f / 32767.0f)

// ---------------- fallback: scatter-atomic (round-1 kernel) ----------------
__global__ __launch_bounds__(256) void lightgcn_scatter(
    const float* __restrict__ user_emb,
    const float* __restrict__ item_emb,
    const float* __restrict__ edge_norm,
    const int* __restrict__ u_idx,
    const int* __restrict__ i_idx,
    float* __restrict__ agg_users,
    float* __restrict__ agg_items)
{
    long long gid = (long long)blockIdx.x * blockDim.x + threadIdx.x;
    int edge = (int)(gid >> 6);
    int lane = (int)(gid & 63);
    if (edge >= NUM_EDGES) return;
    int u = u_idx[edge];
    int i = i_idx[edge];
    float n = edge_norm[edge];
    float uval = user_emb[(size_t)u * DIM + lane];
    float ival = item_emb[(size_t)i * DIM + lane];
    atomicAdd(&agg_items[(size_t)i * DIM + lane], n * uval);
    atomicAdd(&agg_users[(size_t)u * DIM + lane], n * ival);
}

// ---------------- bf16 conversion of embedding tables ----------------
__global__ __launch_bounds__(256) void convert_bf16(
    const float4* __restrict__ src, ushort* __restrict__ dst, int n4)
{
    int t = blockIdx.x * blockDim.x + threadIdx.x;
    if (t >= n4) return;
    float4 v = src[t];
    ushort4 o;
    uint b;
    b = __float_as_uint(v.x); o.x = (ushort)((b + 0x7FFFu + ((b >> 16) & 1u)) >> 16);
    b = __float_as_uint(v.y); o.y = (ushort)((b + 0x7FFFu + ((b >> 16) & 1u)) >> 16);
    b = __float_as_uint(v.z); o.z = (ushort)((b + 0x7FFFu + ((b >> 16) & 1u)) >> 16);
    b = __float_as_uint(v.w); o.w = (ushort)((b + 0x7FFFu + ((b >> 16) & 1u)) >> 16);
    ((ushort4*)dst)[t] = o;
}

// ---------------- CSR build (concatenated bins) ----------------------------
__global__ __launch_bounds__(256) void edge_hist(
    const int4* __restrict__ u4, const int4* __restrict__ i4,
    int* __restrict__ cnt, int n_i, int su_shift, int si_shift)
{
    int t = blockIdx.x * blockDim.x + threadIdx.x;
    if (t >= NUM_EDGES / 4) return;
    int4 u = u4[t];
    int4 i = i4[t];
    atomicAdd(&cnt[(u.x >> su_shift) * NUM_ITEMS + i.x], 1);
    atomicAdd(&cnt[(u.y >> su_shift) * NUM_ITEMS + i.y], 1);
    atomicAdd(&cnt[(u.z >> su_shift) * NUM_ITEMS + i.z], 1);
    atomicAdd(&cnt[(u.w >> su_shift) * NUM_ITEMS + i.w], 1);
    atomicAdd(&cnt[n_i + (i.x >> si_shift) * NUM_USERS + u.x], 1);
    atomicAdd(&cnt[n_i + (i.y >> si_shift) * NUM_USERS + u.y], 1);
    atomicAdd(&cnt[n_i + (i.z >> si_shift) * NUM_USERS + u.z], 1);
    atomicAdd(&cnt[n_i + (i.w >> si_shift) * NUM_USERS + u.w], 1);
}

// ---------------- 3-phase multi-block exclusive scan ----------------------
__global__ __launch_bounds__(SCAN_THREADS) void scan_block_sums(
    const int* __restrict__ cnt, int* __restrict__ bsum, int n, int chunk)
{
    int b = blockIdx.x, t = threadIdx.x;
    int base = b * chunk;
    int end  = base + chunk < n ? base + chunk : n;
    int tch  = (chunk + SCAN_THREADS - 1) / SCAN_THREADS;
    int s = base + t * tch;
    int e = s + tch < end ? s + tch : end;
    int local = 0;
    for (int i = s; i < e; ++i) local += cnt[i];
    __shared__ int sm[SCAN_THREADS];
    sm[t] = local;
    __syncthreads();
    for (int o = SCAN_THREADS / 2; o > 0; o >>= 1) {
        if (t < o) sm[t] += sm[t + o];
        __syncthreads();
    }
    if (t == 0) bsum[b] = sm[0];
}

__global__ __launch_bounds__(SCAN_NB) void scan_block_offsets(
    const int* __restrict__ bsum, int* __restrict__ boff,
    int* __restrict__ off_end)
{
    int t = threadIdx.x;
    __shared__ int sm[SCAN_NB];
    int v = bsum[t];
    sm[t] = v;
    __syncthreads();
    for (int o = 1; o < SCAN_NB; o <<= 1) {
        int x = (t >= o) ? sm[t - o] : 0;
        __syncthreads();
        sm[t] += x;
        __syncthreads();
    }
    boff[t] = sm[t] - v;
    if (t == SCAN_NB - 1) *off_end = sm[SCAN_NB - 1];
}

__global__ __launch_bounds__(SCAN_THREADS) void scan_local(
    int* __restrict__ cnt, int* __restrict__ cur,
    const int* __restrict__ boff, int n, int chunk)
{
    int b = blockIdx.x, t = threadIdx.x;
    int base = b * chunk;
    int end  = base + chunk < n ? base + chunk : n;
    int tch  = (chunk + SCAN_THREADS - 1) / SCAN_THREADS;
    int s = base + t * tch;
    int e = s + tch < end ? s + tch : end;
    int local = 0;
    for (int i = s; i < e; ++i) local += cnt[i];
    __shared__ int sm[SCAN_THREADS];
    sm[t] = local;
    __syncthreads();
    for (int o = 1; o < SCAN_THREADS; o <<= 1) {
        int x = (t >= o) ? sm[t - o] : 0;
        __syncthreads();
        sm[t] += x;
        __syncthreads();
    }
    int run = boff[b] + ((t == 0) ? 0 : sm[t - 1]);
    for (int i = s; i < e; ++i) {
        int c = cnt[i];
        cnt[i] = run;
        cur[i] = run;
        run += c;
    }
}

// ---------------- two-phase placement --------------------------------------
// Phase A: atomics only; positions written COALESCED (no scattered store in
// the same kernel as the atomic -> no dependent-chain serialization).
// dst_idx = CSR key (destination row), sl_idx = source row (slicing key).
__global__ __launch_bounds__(256) void place_pos(
    const int* __restrict__ dst_idx, const int* __restrict__ sl_idx,
    int* __restrict__ cur, int bin_base, int dst_count, int sl_shift,
    int* __restrict__ pos)
{
    int e = blockIdx.x * blockDim.x + threadIdx.x;
    if (e >= NUM_EDGES) return;
    int d = dst_idx[e];
    int s = sl_idx[e];
    pos[e] = atomicAdd(&cur[bin_base + (s >> sl_shift) * dst_count + d], 1);
}

// Phase B: dependency-free scattered stores, 4 edges/thread (8-deep store MLP
// across the two halves of the int4).
__global__ __launch_bounds__(256) void place_scatter(
    const int4* __restrict__ src4, const float4* __restrict__ nrm4,
    const int4* __restrict__ pos4, uint* __restrict__ rec)
{
    int t = blockIdx.x * blockDim.x + threadIdx.x;
    if (t >= NUM_EDGES / 4) return;
    int4   s = src4[t];
    float4 n = nrm4[t];
    int4   p = pos4[t];
    uint w0 = (uint)(n.x * W_SCALE + 0.5f); if (w0 > 32767u) w0 = 32767u;
    uint w1 = (uint)(n.y * W_SCALE + 0.5f); if (w1 > 32767u) w1 = 32767u;
    uint w2 = (uint)(n.z * W_SCALE + 0.5f); if (w2 > 32767u) w2 = 32767u;
    uint w3 = (uint)(n.w * W_SCALE + 0.5f); if (w3 > 32767u) w3 = 32767u;
    rec[p.x] = ((uint)s.x << 15) | w0;
    rec[p.y] = ((uint)s.y << 15) | w1;
    rec[p.z] = ((uint)s.z << 15) | w2;
    rec[p.w] = ((uint)s.w << 15) | w3;
}

// ---------------- gather pass: one 64-lane wave per dst row, one src slice --
__global__ __launch_bounds__(256) void gather_pass(
    const int* __restrict__ off, int bin_base,
    const uint* __restrict__ rec,
    const ushort* __restrict__ emb16,
    float* __restrict__ out, int nrows, int accumulate)
{
    int gid  = blockIdx.x * blockDim.x + threadIdx.x;
    int row  = gid >> 6;
    int lane = gid & 63;
    if (row >= nrows) return;
    int b = bin_base + row;
    int s = off[b];
    int e = off[b + 1];
    float acc = accumulate ? out[(size_t)row * DIM + lane] : 0.f;
    int k = s;
    for (; k + 8 <= e; k += 8) {
        uint r0 = rec[k],   r1 = rec[k+1], r2 = rec[k+2], r3 = rec[k+3];
        uint r4 = rec[k+4], r5 = rec[k+5], r6 = rec[k+6], r7 = rec[k+7];
        ushort b0 = emb16[(size_t)(r0 >> 15) * DIM + lane];
        ushort b1 = emb16[(size_t)(r1 >> 15) * DIM + lane];
        ushort b2 = emb16[(size_t)(r2 >> 15) * DIM + lane];
        ushort b3 = emb16[(size_t)(r3 >> 15) * DIM + lane];
        ushort b4 = emb16[(size_t)(r4 >> 15) * DIM + lane];
        ushort b5 = emb16[(size_t)(r5 >> 15) * DIM + lane];
        ushort b6 = emb16[(size_t)(r6 >> 15) * DIM + lane];
        ushort b7 = emb16[(size_t)(r7 >> 15) * DIM + lane];
        acc += (float)(r0 & 0x7FFFu) * W_INV * __uint_as_float((uint)b0 << 16);
        acc += (float)(r1 & 0x7FFFu) * W_INV * __uint_as_float((uint)b1 << 16);
        acc += (float)(r2 & 0x7FFFu) * W_INV * __uint_as_float((uint)b2 << 16);
        acc += (float)(r3 & 0x7FFFu) * W_INV * __uint_as_float((uint)b3 << 16);
        acc += (float)(r4 & 0x7FFFu) * W_INV * __uint_as_float((uint)b4 << 16);
        acc += (float)(r5 & 0x7FFFu) * W_INV * __uint_as_float((uint)b5 << 16);
        acc += (float)(r6 & 0x7FFFu) * W_INV * __uint_as_float((uint)b6 << 16);
        acc += (float)(r7 & 0x7FFFu) * W_INV * __uint_as_float((uint)b7 << 16);
    }
    for (; k + 4 <= e; k += 4) {
        uint r0 = rec[k], r1 = rec[k+1], r2 = rec[k+2], r3 = rec[k+3];
        ushort b0 = emb16[(size_t)(r0 >> 15) * DIM + lane];
        ushort b1 = emb16[(size_t)(r1 >> 15) * DIM + lane];
        ushort b2 = emb16[(size_t)(r2 >> 15) * DIM + lane];
        ushort b3 = emb16[(size_t)(r3 >> 15) * DIM + lane];
        acc += (float)(r0 & 0x7FFFu) * W_INV * __uint_as_float((uint)b0 << 16);
        acc += (float)(r1 & 0x7FFFu) * W_INV * __uint_as_float((uint)b1 << 16);
        acc += (float)(r2 & 0x7FFFu) * W_INV * __uint_as_float((uint)b2 << 16);
        acc += (float)(r3 & 0x7FFFu) * W_INV * __uint_as_float((uint)b3 << 16);
    }
    for (; k < e; ++k) {
        uint r0 = rec[k];
        ushort b0 = emb16[(size_t)(r0 >> 15) * DIM + lane];
        acc += (float)(r0 & 0x7FFFu) * W_INV * __uint_as_float((uint)b0 << 16);
    }
    out[(size_t)row * DIM + lane] = acc;
}

extern "C" void kernel_launch(void* const* d_in, const int* in_sizes, int n_in,
                              void* d_out, int out_size, void* d_ws, size_t ws_size,
                              hipStream_t stream) {
    const float* user_emb  = (const float*)d_in[0];
    const float* item_emb  = (const float*)d_in[1];
    const float* edge_norm = (const float*)d_in[2];
    const int*   u_idx     = (const int*)d_in[3];
    const int*   i_idx     = (const int*)d_in[4];

    float* agg_users = (float*)d_out;                        // 100000*64
    float* agg_items = agg_users + (size_t)NUM_USERS * DIM;  // 50000*64

    const size_t rec_bytes  = (size_t)2 * NUM_EDGES * sizeof(uint);
    const size_t pos_bytes  = (size_t)NUM_EDGES * sizeof(int);
    const size_t bf16_bytes = ((size_t)NUM_USERS + NUM_ITEMS) * DIM * sizeof(ushort);
    auto need_for = [&](int SU, int SI) -> size_t {
        size_t n_total = (size_t)SU * NUM_ITEMS + (size_t)SI * NUM_USERS;
        size_t off_bytes = (2 * n_total + 1 + 2 * SCAN_NB) * sizeof(int);
        return off_bytes + 64 + rec_bytes + 64 + pos_bytes + 64 + bf16_bytes;
    };

    int SU, SI, su_shift, si_shift;
    if (ws_size >= need_for(SLICES_U, SLICES_I)) {
        SU = SLICES_U; SI = SLICES_I;
        su_shift = SLICE_SHIFT; si_shift = SLICE_SHIFT;
    } else if (ws_size >= need_for(1, 1)) {
        SU = 1; SI = 1;
        su_shift = 17; si_shift = 17;
    } else {
        hipMemsetAsync(d_out, 0, (size_t)out_size * sizeof(float), stream);
        const long long total_threads = (long long)NUM_EDGES * 64;
        const int blocks = (int)((total_threads + 255) / 256);
        lightgcn_scatter<<<blocks, 256, 0, stream>>>(
            user_emb, item_emb, edge_norm, u_idx, i_idx, agg_users, agg_items);
        return;
    }

    const int n_i = SU * NUM_ITEMS;
    const int n_u = SI * NUM_USERS;
    const int n_total = n_i + n_u;

    char* p = (char*)d_ws;
    int*   cnt  = (int*)p;   p += (size_t)(n_total + 1) * sizeof(int);
    int*   cur  = (int*)p;   p += (size_t)n_total * sizeof(int);
    int*   bsum = (int*)p;   p += (size_t)SCAN_NB * sizeof(int);
    int*   boff = (int*)p;   p += (size_t)SCAN_NB * sizeof(int);
    p = (char*)(((uintptr_t)p + 63) & ~(uintptr_t)63);
    uint*  rec  = (uint*)p;  p += rec_bytes;
    p = (char*)(((uintptr_t)p + 63) & ~(uintptr_t)63);
    int*   pos  = (int*)p;   p += pos_bytes;
    p = (char*)(((uintptr_t)p + 63) & ~(uintptr_t)63);
    ushort* ue16 = (ushort*)p; p += (size_t)NUM_USERS * DIM * sizeof(ushort);
    ushort* ie16 = (ushort*)p;

    hipMemsetAsync(cnt, 0, (size_t)(n_total + 1) * sizeof(int), stream);

    const int un4 = NUM_USERS * DIM / 4;
    const int in4 = NUM_ITEMS * DIM / 4;
    convert_bf16<<<(un4 + 255) / 256, 256, 0, stream>>>(
        (const float4*)user_emb, ue16, un4);
    convert_bf16<<<(in4 + 255) / 256, 256, 0, stream>>>(
        (const float4*)item_emb, ie16, in4);

    edge_hist<<<(NUM_EDGES / 4 + 255) / 256, 256, 0, stream>>>(
        (const int4*)u_idx, (const int4*)i_idx, cnt, n_i, su_shift, si_shift);

    const int chunk = (n_total + SCAN_NB - 1) / SCAN_NB;
    scan_block_sums<<<SCAN_NB, SCAN_THREADS, 0, stream>>>(cnt, bsum, n_total, chunk);
    scan_block_offsets<<<1, SCAN_NB, 0, stream>>>(bsum, boff, cnt + n_total);
    scan_local<<<SCAN_NB, SCAN_THREADS, 0, stream>>>(cnt, cur, boff, n_total, chunk);

    const int eb  = (NUM_EDGES + 255) / 256;
    const int eb4 = (NUM_EDGES / 4 + 255) / 256;

    // items-direction: bins keyed (u_slice, i); record value = u
    place_pos<<<eb, 256, 0, stream>>>(i_idx, u_idx, cur, 0, NUM_ITEMS,
                                      su_shift, pos);
    place_scatter<<<eb4, 256, 0, stream>>>(
        (const int4*)u_idx, (const float4*)edge_norm, (const int4*)pos, rec);

    // users-direction: bins keyed (i_slice, u); record value = i  (pos reused)
    place_pos<<<eb, 256, 0, stream>>>(u_idx, i_idx, cur, n_i, NUM_USERS,
                                      si_shift, pos);
    place_scatter<<<eb4, 256, 0, stream>>>(
        (const int4*)i_idx, (const float4*)edge_norm, (const int4*)pos, rec);

    // agg_items: gather user rows, one launch per user-table slice
    for (int s = 0; s < SU; ++s) {
        gather_pass<<<((NUM_ITEMS * 64) + 255) / 256, 256, 0, stream>>>(
            cnt, s * NUM_ITEMS, rec, ue16, agg_items, NUM_ITEMS, s > 0 ? 1 : 0);
    }
    // agg_users: gather item rows, one launch per item-table slice
    for (int s = 0; s < SI; ++s) {
        gather_pass<<<((NUM_USERS * 64) + 255) / 256, 256, 0, stream>>>(
            cnt, n_i + s * NUM_USERS, rec, ie16, agg_users, NUM_USERS,
            s > 0 ? 1 : 0);
    }
}

// Round 9
// 936.832 us; speedup vs baseline: 1.3502x; 1.2241x over previous
//
#include <hip/hip_runtime.h>

#define NUM_USERS 100000
#define NUM_ITEMS 50000
#define NUM_EDGES 4000000
#define DIM 64

// Source-table slicing: 1<<14 = 16384 rows/slice = 2 MB bf16 per slice.
#define SLICE_SHIFT 14
#define SLICES_U ((NUM_USERS + (1 << SLICE_SHIFT) - 1) >> SLICE_SHIFT)  // 7
#define SLICES_I ((NUM_ITEMS + (1 << SLICE_SHIFT) - 1) >> SLICE_SHIFT)  // 4

#define SCAN_NB 512
#define SCAN_THREADS 256

// Packed CSR record: (src_row << 15) | w_quant15 (err <= 1.5e-5 << bf16 noise).
#define W_SCALE 32767.0f
#define W_INV   (1.0f / 32767.0f)

// ---------------- fallback: scatter-atomic (round-1 kernel) ----------------
__global__ __launch_bounds__(256) void lightgcn_scatter(
    const float* __restrict__ user_emb,
    const float* __restrict__ item_emb,
    const float* __restrict__ edge_norm,
    const int* __restrict__ u_idx,
    const int* __restrict__ i_idx,
    float* __restrict__ agg_users,
    float* __restrict__ agg_items)
{
    long long gid = (long long)blockIdx.x * blockDim.x + threadIdx.x;
    int edge = (int)(gid >> 6);
    int lane = (int)(gid & 63);
    if (edge >= NUM_EDGES) return;
    int u = u_idx[edge];
    int i = i_idx[edge];
    float n = edge_norm[edge];
    float uval = user_emb[(size_t)u * DIM + lane];
    float ival = item_emb[(size_t)i * DIM + lane];
    atomicAdd(&agg_items[(size_t)i * DIM + lane], n * uval);
    atomicAdd(&agg_users[(size_t)u * DIM + lane], n * ival);
}

// ---------------- bf16 conversion of embedding tables ----------------
__global__ __launch_bounds__(256) void convert_bf16(
    const float4* __restrict__ src, ushort* __restrict__ dst, int n4)
{
    int t = blockIdx.x * blockDim.x + threadIdx.x;
    if (t >= n4) return;
    float4 v = src[t];
    ushort4 o;
    uint b;
    b = __float_as_uint(v.x); o.x = (ushort)((b + 0x7FFFu + ((b >> 16) & 1u)) >> 16);
    b = __float_as_uint(v.y); o.y = (ushort)((b + 0x7FFFu + ((b >> 16) & 1u)) >> 16);
    b = __float_as_uint(v.z); o.z = (ushort)((b + 0x7FFFu + ((b >> 16) & 1u)) >> 16);
    b = __float_as_uint(v.w); o.w = (ushort)((b + 0x7FFFu + ((b >> 16) & 1u)) >> 16);
    ((ushort4*)dst)[t] = o;
}

// ---------------- rank + count in ONE atomic pass ---------------------------
// Returning atomicAdd on zeroed cnt gives each edge its within-bin rank
// (written COALESCED) and leaves cnt holding the per-bin counts for the scan.
// This replaces the separate hist + place_pos passes (8M+8M atomics -> 8M).
__global__ __launch_bounds__(256) void rank_both(
    const int4* __restrict__ u4, const int4* __restrict__ i4,
    int* __restrict__ cnt, int n_i, int su_shift, int si_shift,
    int4* __restrict__ rank_i, int4* __restrict__ rank_u)
{
    int t = blockIdx.x * blockDim.x + threadIdx.x;
    if (t >= NUM_EDGES / 4) return;
    int4 u = u4[t];
    int4 i = i4[t];
    int4 ri, ru;
    ri.x = atomicAdd(&cnt[(u.x >> su_shift) * NUM_ITEMS + i.x], 1);
    ri.y = atomicAdd(&cnt[(u.y >> su_shift) * NUM_ITEMS + i.y], 1);
    ri.z = atomicAdd(&cnt[(u.z >> su_shift) * NUM_ITEMS + i.z], 1);
    ri.w = atomicAdd(&cnt[(u.w >> su_shift) * NUM_ITEMS + i.w], 1);
    ru.x = atomicAdd(&cnt[n_i + (i.x >> si_shift) * NUM_USERS + u.x], 1);
    ru.y = atomicAdd(&cnt[n_i + (i.y >> si_shift) * NUM_USERS + u.y], 1);
    ru.z = atomicAdd(&cnt[n_i + (i.z >> si_shift) * NUM_USERS + u.z], 1);
    ru.w = atomicAdd(&cnt[n_i + (i.w >> si_shift) * NUM_USERS + u.w], 1);
    rank_i[t] = ri;
    rank_u[t] = ru;
}

// ---------------- 3-phase multi-block exclusive scan ----------------------
__global__ __launch_bounds__(SCAN_THREADS) void scan_block_sums(
    const int* __restrict__ cnt, int* __restrict__ bsum, int n, int chunk)
{
    int b = blockIdx.x, t = threadIdx.x;
    int base = b * chunk;
    int end  = base + chunk < n ? base + chunk : n;
    int tch  = (chunk + SCAN_THREADS - 1) / SCAN_THREADS;
    int s = base + t * tch;
    int e = s + tch < end ? s + tch : end;
    int local = 0;
    for (int i = s; i < e; ++i) local += cnt[i];
    __shared__ int sm[SCAN_THREADS];
    sm[t] = local;
    __syncthreads();
    for (int o = SCAN_THREADS / 2; o > 0; o >>= 1) {
        if (t < o) sm[t] += sm[t + o];
        __syncthreads();
    }
    if (t == 0) bsum[b] = sm[0];
}

__global__ __launch_bounds__(SCAN_NB) void scan_block_offsets(
    const int* __restrict__ bsum, int* __restrict__ boff,
    int* __restrict__ off_end)
{
    int t = threadIdx.x;
    __shared__ int sm[SCAN_NB];
    int v = bsum[t];
    sm[t] = v;
    __syncthreads();
    for (int o = 1; o < SCAN_NB; o <<= 1) {
        int x = (t >= o) ? sm[t - o] : 0;
        __syncthreads();
        sm[t] += x;
        __syncthreads();
    }
    boff[t] = sm[t] - v;
    if (t == SCAN_NB - 1) *off_end = sm[SCAN_NB - 1];
}

// in-place: cnt -> exclusive offsets (no cursor copy needed anymore)
__global__ __launch_bounds__(SCAN_THREADS) void scan_local(
    int* __restrict__ cnt, const int* __restrict__ boff, int n, int chunk)
{
    int b = blockIdx.x, t = threadIdx.x;
    int base = b * chunk;
    int end  = base + chunk < n ? base + chunk : n;
    int tch  = (chunk + SCAN_THREADS - 1) / SCAN_THREADS;
    int s = base + t * tch;
    int e = s + tch < end ? s + tch : end;
    int local = 0;
    for (int i = s; i < e; ++i) local += cnt[i];
    __shared__ int sm[SCAN_THREADS];
    sm[t] = local;
    __syncthreads();
    for (int o = 1; o < SCAN_THREADS; o <<= 1) {
        int x = (t >= o) ? sm[t - o] : 0;
        __syncthreads();
        sm[t] += x;
        __syncthreads();
    }
    int run = boff[b] + ((t == 0) ? 0 : sm[t - 1]);
    for (int i = s; i < e; ++i) {
        int c = cnt[i];
        cnt[i] = run;
        run += c;
    }
}

// ---------------- scatter: pos = off[bin] + rank, both directions fused -----
// No atomics; 8 independent scattered 4B stores per thread; off[] reads are
// read-only (L1/L2-replicable across XCDs, ~11 edges share each bin).
__global__ __launch_bounds__(256) void scatter_all(
    const int4* __restrict__ u4, const int4* __restrict__ i4,
    const float4* __restrict__ n4,
    const int4* __restrict__ rank_i, const int4* __restrict__ rank_u,
    const int* __restrict__ off, int n_i, int su_shift, int si_shift,
    uint* __restrict__ rec)
{
    int t = blockIdx.x * blockDim.x + threadIdx.x;
    if (t >= NUM_EDGES / 4) return;
    int4   u  = u4[t];
    int4   i  = i4[t];
    float4 n  = n4[t];
    int4   ri = rank_i[t];
    int4   ru = rank_u[t];
    uint w0 = (uint)(n.x * W_SCALE + 0.5f); if (w0 > 32767u) w0 = 32767u;
    uint w1 = (uint)(n.y * W_SCALE + 0.5f); if (w1 > 32767u) w1 = 32767u;
    uint w2 = (uint)(n.z * W_SCALE + 0.5f); if (w2 > 32767u) w2 = 32767u;
    uint w3 = (uint)(n.w * W_SCALE + 0.5f); if (w3 > 32767u) w3 = 32767u;
    int pi0 = off[(u.x >> su_shift) * NUM_ITEMS + i.x] + ri.x;
    int pi1 = off[(u.y >> su_shift) * NUM_ITEMS + i.y] + ri.y;
    int pi2 = off[(u.z >> su_shift) * NUM_ITEMS + i.z] + ri.z;
    int pi3 = off[(u.w >> su_shift) * NUM_ITEMS + i.w] + ri.w;
    int pu0 = off[n_i + (i.x >> si_shift) * NUM_USERS + u.x] + ru.x;
    int pu1 = off[n_i + (i.y >> si_shift) * NUM_USERS + u.y] + ru.y;
    int pu2 = off[n_i + (i.z >> si_shift) * NUM_USERS + u.z] + ru.z;
    int pu3 = off[n_i + (i.w >> si_shift) * NUM_USERS + u.w] + ru.w;
    rec[pi0] = ((uint)u.x << 15) | w0;
    rec[pi1] = ((uint)u.y << 15) | w1;
    rec[pi2] = ((uint)u.z << 15) | w2;
    rec[pi3] = ((uint)u.w << 15) | w3;
    rec[pu0] = ((uint)i.x << 15) | w0;
    rec[pu1] = ((uint)i.y << 15) | w1;
    rec[pu2] = ((uint)i.z << 15) | w2;
    rec[pu3] = ((uint)i.w << 15) | w3;
}

// ---------------- gather pass: one 64-lane wave per dst row, one src slice --
__global__ __launch_bounds__(256) void gather_pass(
    const int* __restrict__ off, int bin_base,
    const uint* __restrict__ rec,
    const ushort* __restrict__ emb16,
    float* __restrict__ out, int nrows, int accumulate)
{
    int gid  = blockIdx.x * blockDim.x + threadIdx.x;
    int row  = gid >> 6;
    int lane = gid & 63;
    if (row >= nrows) return;
    int b = bin_base + row;
    int s = off[b];
    int e = off[b + 1];
    float acc = accumulate ? out[(size_t)row * DIM + lane] : 0.f;
    int k = s;
    for (; k + 8 <= e; k += 8) {
        uint r0 = rec[k],   r1 = rec[k+1], r2 = rec[k+2], r3 = rec[k+3];
        uint r4 = rec[k+4], r5 = rec[k+5], r6 = rec[k+6], r7 = rec[k+7];
        ushort b0 = emb16[(size_t)(r0 >> 15) * DIM + lane];
        ushort b1 = emb16[(size_t)(r1 >> 15) * DIM + lane];
        ushort b2 = emb16[(size_t)(r2 >> 15) * DIM + lane];
        ushort b3 = emb16[(size_t)(r3 >> 15) * DIM + lane];
        ushort b4 = emb16[(size_t)(r4 >> 15) * DIM + lane];
        ushort b5 = emb16[(size_t)(r5 >> 15) * DIM + lane];
        ushort b6 = emb16[(size_t)(r6 >> 15) * DIM + lane];
        ushort b7 = emb16[(size_t)(r7 >> 15) * DIM + lane];
        acc += (float)(r0 & 0x7FFFu) * W_INV * __uint_as_float((uint)b0 << 16);
        acc += (float)(r1 & 0x7FFFu) * W_INV * __uint_as_float((uint)b1 << 16);
        acc += (float)(r2 & 0x7FFFu) * W_INV * __uint_as_float((uint)b2 << 16);
        acc += (float)(r3 & 0x7FFFu) * W_INV * __uint_as_float((uint)b3 << 16);
        acc += (float)(r4 & 0x7FFFu) * W_INV * __uint_as_float((uint)b4 << 16);
        acc += (float)(r5 & 0x7FFFu) * W_INV * __uint_as_float((uint)b5 << 16);
        acc += (float)(r6 & 0x7FFFu) * W_INV * __uint_as_float((uint)b6 << 16);
        acc += (float)(r7 & 0x7FFFu) * W_INV * __uint_as_float((uint)b7 << 16);
    }
    for (; k + 4 <= e; k += 4) {
        uint r0 = rec[k], r1 = rec[k+1], r2 = rec[k+2], r3 = rec[k+3];
        ushort b0 = emb16[(size_t)(r0 >> 15) * DIM + lane];
        ushort b1 = emb16[(size_t)(r1 >> 15) * DIM + lane];
        ushort b2 = emb16[(size_t)(r2 >> 15) * DIM + lane];
        ushort b3 = emb16[(size_t)(r3 >> 15) * DIM + lane];
        acc += (float)(r0 & 0x7FFFu) * W_INV * __uint_as_float((uint)b0 << 16);
        acc += (float)(r1 & 0x7FFFu) * W_INV * __uint_as_float((uint)b1 << 16);
        acc += (float)(r2 & 0x7FFFu) * W_INV * __uint_as_float((uint)b2 << 16);
        acc += (float)(r3 & 0x7FFFu) * W_INV * __uint_as_float((uint)b3 << 16);
    }
    for (; k < e; ++k) {
        uint r0 = rec[k];
        ushort b0 = emb16[(size_t)(r0 >> 15) * DIM + lane];
        acc += (float)(r0 & 0x7FFFu) * W_INV * __uint_as_float((uint)b0 << 16);
    }
    out[(size_t)row * DIM + lane] = acc;
}

extern "C" void kernel_launch(void* const* d_in, const int* in_sizes, int n_in,
                              void* d_out, int out_size, void* d_ws, size_t ws_size,
                              hipStream_t stream) {
    const float* user_emb  = (const float*)d_in[0];
    const float* item_emb  = (const float*)d_in[1];
    const float* edge_norm = (const float*)d_in[2];
    const int*   u_idx     = (const int*)d_in[3];
    const int*   i_idx     = (const int*)d_in[4];

    float* agg_users = (float*)d_out;                        // 100000*64
    float* agg_items = agg_users + (size_t)NUM_USERS * DIM;  // 50000*64

    const size_t rec_bytes  = (size_t)2 * NUM_EDGES * sizeof(uint);
    const size_t rank_bytes = (size_t)2 * NUM_EDGES * sizeof(int);
    const size_t bf16_bytes = ((size_t)NUM_USERS + NUM_ITEMS) * DIM * sizeof(ushort);
    auto need_for = [&](int SU, int SI) -> size_t {
        size_t n_total = (size_t)SU * NUM_ITEMS + (size_t)SI * NUM_USERS;
        size_t off_bytes = (n_total + 1 + 2 * SCAN_NB) * sizeof(int);
        return off_bytes + 64 + rec_bytes + 64 + rank_bytes + 64 + bf16_bytes;
    };

    int SU, SI, su_shift, si_shift;
    if (ws_size >= need_for(SLICES_U, SLICES_I)) {
        SU = SLICES_U; SI = SLICES_I;
        su_shift = SLICE_SHIFT; si_shift = SLICE_SHIFT;
    } else if (ws_size >= need_for(1, 1)) {
        SU = 1; SI = 1;
        su_shift = 17; si_shift = 17;
    } else {
        hipMemsetAsync(d_out, 0, (size_t)out_size * sizeof(float), stream);
        const long long total_threads = (long long)NUM_EDGES * 64;
        const int blocks = (int)((total_threads + 255) / 256);
        lightgcn_scatter<<<blocks, 256, 0, stream>>>(
            user_emb, item_emb, edge_norm, u_idx, i_idx, agg_users, agg_items);
        return;
    }

    const int n_i = SU * NUM_ITEMS;
    const int n_u = SI * NUM_USERS;
    const int n_total = n_i + n_u;

    char* p = (char*)d_ws;
    int*   cnt  = (int*)p;   p += (size_t)(n_total + 1) * sizeof(int);
    int*   bsum = (int*)p;   p += (size_t)SCAN_NB * sizeof(int);
    int*   boff = (int*)p;   p += (size_t)SCAN_NB * sizeof(int);
    p = (char*)(((uintptr_t)p + 63) & ~(uintptr_t)63);
    uint*  rec  = (uint*)p;  p += rec_bytes;
    p = (char*)(((uintptr_t)p + 63) & ~(uintptr_t)63);
    int*   rank_i = (int*)p; p += (size_t)NUM_EDGES * sizeof(int);
    int*   rank_u = (int*)p; p += (size_t)NUM_EDGES * sizeof(int);
    p = (char*)(((uintptr_t)p + 63) & ~(uintptr_t)63);
    ushort* ue16 = (ushort*)p; p += (size_t)NUM_USERS * DIM * sizeof(ushort);
    ushort* ie16 = (ushort*)p;

    hipMemsetAsync(cnt, 0, (size_t)(n_total + 1) * sizeof(int), stream);

    const int un4 = NUM_USERS * DIM / 4;
    const int in4 = NUM_ITEMS * DIM / 4;
    convert_bf16<<<(un4 + 255) / 256, 256, 0, stream>>>(
        (const float4*)user_emb, ue16, un4);
    convert_bf16<<<(in4 + 255) / 256, 256, 0, stream>>>(
        (const float4*)item_emb, ie16, in4);

    const int eb4 = (NUM_EDGES / 4 + 255) / 256;

    // one atomic pass: ranks (coalesced) + counts
    rank_both<<<eb4, 256, 0, stream>>>(
        (const int4*)u_idx, (const int4*)i_idx, cnt, n_i, su_shift, si_shift,
        (int4*)rank_i, (int4*)rank_u);

    const int chunk = (n_total + SCAN_NB - 1) / SCAN_NB;
    scan_block_sums<<<SCAN_NB, SCAN_THREADS, 0, stream>>>(cnt, bsum, n_total, chunk);
    scan_block_offsets<<<1, SCAN_NB, 0, stream>>>(bsum, boff, cnt + n_total);
    scan_local<<<SCAN_NB, SCAN_THREADS, 0, stream>>>(cnt, boff, n_total, chunk);

    // atomic-free scatter, both directions fused
    scatter_all<<<eb4, 256, 0, stream>>>(
        (const int4*)u_idx, (const int4*)i_idx, (const float4*)edge_norm,
        (const int4*)rank_i, (const int4*)rank_u,
        cnt, n_i, su_shift, si_shift, rec);

    // agg_items: gather user rows, one launch per user-table slice
    for (int s = 0; s < SU; ++s) {
        gather_pass<<<((NUM_ITEMS * 64) + 255) / 256, 256, 0, stream>>>(
            cnt, s * NUM_ITEMS, rec, ue16, agg_items, NUM_ITEMS, s > 0 ? 1 : 0);
    }
    // agg_users: gather item rows, one launch per item-table slice
    for (int s = 0; s < SI; ++s) {
        gather_pass<<<((NUM_USERS * 64) + 255) / 256, 256, 0, stream>>>(
            cnt, n_i + s * NUM_USERS, rec, ie16, agg_users, NUM_USERS,
            s > 0 ? 1 : 0);
    }
}

// Round 10
// 885.280 us; speedup vs baseline: 1.4289x; 1.0582x over previous
//
#include <hip/hip_runtime.h>

#define NUM_USERS 100000
#define NUM_ITEMS 50000
#define NUM_EDGES 4000000
#define DIM 64

// Source-table slicing: 1<<14 = 16384 rows/slice = 2 MB bf16 per slice.
#define SLICE_SHIFT 14
#define SLICES_U ((NUM_USERS + (1 << SLICE_SHIFT) - 1) >> SLICE_SHIFT)  // 7
#define SLICES_I ((NUM_ITEMS + (1 << SLICE_SHIFT) - 1) >> SLICE_SHIFT)  // 4

#define SCAN_NB 512
#define SCAN_THREADS 256

// Padded-bin capacity: 48 recs = 192 B = 3 cache lines per bin.
// P(Poisson(11.4) >= 48) ~ 1e-14/bin -> no overflow across 750K bins; gather
// clamps len<=C anyway.
#define PAD_CAP 48

// Packed CSR record: (src_row << 15) | w_quant15 (err <= 1.5e-5 << bf16 noise).
#define W_SCALE 32767.0f
#define W_INV   (1.0f / 32767.0f)

// ---------------- fallback: scatter-atomic (round-1 kernel) ----------------
__global__ __launch_bounds__(256) void lightgcn_scatter(
    const float* __restrict__ user_emb,
    const float* __restrict__ item_emb,
    const float* __restrict__ edge_norm,
    const int* __restrict__ u_idx,
    const int* __restrict__ i_idx,
    float* __restrict__ agg_users,
    float* __restrict__ agg_items)
{
    long long gid = (long long)blockIdx.x * blockDim.x + threadIdx.x;
    int edge = (int)(gid >> 6);
    int lane = (int)(gid & 63);
    if (edge >= NUM_EDGES) return;
    int u = u_idx[edge];
    int i = i_idx[edge];
    float n = edge_norm[edge];
    float uval = user_emb[(size_t)u * DIM + lane];
    float ival = item_emb[(size_t)i * DIM + lane];
    atomicAdd(&agg_items[(size_t)i * DIM + lane], n * uval);
    atomicAdd(&agg_users[(size_t)u * DIM + lane], n * ival);
}

// ---------------- bf16 conversion of BOTH embedding tables (one launch) ----
__global__ __launch_bounds__(256) void convert_both(
    const float4* __restrict__ usrc, const float4* __restrict__ isrc,
    ushort4* __restrict__ udst, ushort4* __restrict__ idst,
    int un4, int in4)
{
    int t = blockIdx.x * blockDim.x + threadIdx.x;
    const float4* s; ushort4* d; int idx;
    if (t < un4) { s = usrc; d = udst; idx = t; }
    else if (t < un4 + in4) { s = isrc; d = idst; idx = t - un4; }
    else return;
    float4 v = s[idx];
    ushort4 o;
    uint b;
    b = __float_as_uint(v.x); o.x = (ushort)((b + 0x7FFFu + ((b >> 16) & 1u)) >> 16);
    b = __float_as_uint(v.y); o.y = (ushort)((b + 0x7FFFu + ((b >> 16) & 1u)) >> 16);
    b = __float_as_uint(v.z); o.z = (ushort)((b + 0x7FFFu + ((b >> 16) & 1u)) >> 16);
    b = __float_as_uint(v.w); o.w = (ushort)((b + 0x7FFFu + ((b >> 16) & 1u)) >> 16);
    d[idx] = o;
}

// ---------------- rank + count in ONE atomic pass (ushort ranks) ------------
__global__ __launch_bounds__(256) void rank_both(
    const int4* __restrict__ u4, const int4* __restrict__ i4,
    int* __restrict__ cnt, int n_i, int su_shift, int si_shift,
    ushort4* __restrict__ rank_i, ushort4* __restrict__ rank_u)
{
    int t = blockIdx.x * blockDim.x + threadIdx.x;
    if (t >= NUM_EDGES / 4) return;
    int4 u = u4[t];
    int4 i = i4[t];
    ushort4 ri, ru;
    ri.x = (ushort)atomicAdd(&cnt[(u.x >> su_shift) * NUM_ITEMS + i.x], 1);
    ri.y = (ushort)atomicAdd(&cnt[(u.y >> su_shift) * NUM_ITEMS + i.y], 1);
    ri.z = (ushort)atomicAdd(&cnt[(u.z >> su_shift) * NUM_ITEMS + i.z], 1);
    ri.w = (ushort)atomicAdd(&cnt[(u.w >> su_shift) * NUM_ITEMS + i.w], 1);
    ru.x = (ushort)atomicAdd(&cnt[n_i + (i.x >> si_shift) * NUM_USERS + u.x], 1);
    ru.y = (ushort)atomicAdd(&cnt[n_i + (i.y >> si_shift) * NUM_USERS + u.y], 1);
    ru.z = (ushort)atomicAdd(&cnt[n_i + (i.z >> si_shift) * NUM_USERS + u.z], 1);
    ru.w = (ushort)atomicAdd(&cnt[n_i + (i.w >> si_shift) * NUM_USERS + u.w], 1);
    rank_i[t] = ri;
    rank_u[t] = ru;
}

// ---------------- padded scatter: pos = bin*PAD_CAP + rank, no scan/off -----
__global__ __launch_bounds__(256) void scatter_pad(
    const int4* __restrict__ u4, const int4* __restrict__ i4,
    const float4* __restrict__ n4,
    const ushort4* __restrict__ rank_i, const ushort4* __restrict__ rank_u,
    int n_i, int su_shift, int si_shift,
    uint* __restrict__ rec)
{
    int t = blockIdx.x * blockDim.x + threadIdx.x;
    if (t >= NUM_EDGES / 4) return;
    int4    u  = u4[t];
    int4    i  = i4[t];
    float4  n  = n4[t];
    ushort4 ri = rank_i[t];
    ushort4 ru = rank_u[t];
    uint w0 = (uint)(n.x * W_SCALE + 0.5f); if (w0 > 32767u) w0 = 32767u;
    uint w1 = (uint)(n.y * W_SCALE + 0.5f); if (w1 > 32767u) w1 = 32767u;
    uint w2 = (uint)(n.z * W_SCALE + 0.5f); if (w2 > 32767u) w2 = 32767u;
    uint w3 = (uint)(n.w * W_SCALE + 0.5f); if (w3 > 32767u) w3 = 32767u;
    size_t pi0 = (size_t)((u.x >> su_shift) * NUM_ITEMS + i.x) * PAD_CAP + ri.x;
    size_t pi1 = (size_t)((u.y >> su_shift) * NUM_ITEMS + i.y) * PAD_CAP + ri.y;
    size_t pi2 = (size_t)((u.z >> su_shift) * NUM_ITEMS + i.z) * PAD_CAP + ri.z;
    size_t pi3 = (size_t)((u.w >> su_shift) * NUM_ITEMS + i.w) * PAD_CAP + ri.w;
    size_t pu0 = (size_t)(n_i + (i.x >> si_shift) * NUM_USERS + u.x) * PAD_CAP + ru.x;
    size_t pu1 = (size_t)(n_i + (i.y >> si_shift) * NUM_USERS + u.y) * PAD_CAP + ru.y;
    size_t pu2 = (size_t)(n_i + (i.z >> si_shift) * NUM_USERS + u.z) * PAD_CAP + ru.z;
    size_t pu3 = (size_t)(n_i + (i.w >> si_shift) * NUM_USERS + u.w) * PAD_CAP + ru.w;
    if (ri.x < PAD_CAP) rec[pi0] = ((uint)u.x << 15) | w0;
    if (ri.y < PAD_CAP) rec[pi1] = ((uint)u.y << 15) | w1;
    if (ri.z < PAD_CAP) rec[pi2] = ((uint)u.z << 15) | w2;
    if (ri.w < PAD_CAP) rec[pi3] = ((uint)u.w << 15) | w3;
    if (ru.x < PAD_CAP) rec[pu0] = ((uint)i.x << 15) | w0;
    if (ru.y < PAD_CAP) rec[pu1] = ((uint)i.y << 15) | w1;
    if (ru.z < PAD_CAP) rec[pu2] = ((uint)i.z << 15) | w2;
    if (ru.w < PAD_CAP) rec[pu3] = ((uint)i.w << 15) | w3;
}

// ---------------- padded gather: one 64-lane wave per dst row ---------------
__global__ __launch_bounds__(256) void gather_pad(
    const int* __restrict__ cnt, int bin_base,
    const uint* __restrict__ rec,
    const ushort* __restrict__ emb16,
    float* __restrict__ out, int nrows, int accumulate)
{
    int gid  = blockIdx.x * blockDim.x + threadIdx.x;
    int row  = gid >> 6;
    int lane = gid & 63;
    if (row >= nrows) return;
    int b = bin_base + row;
    int len = cnt[b];
    if (len > PAD_CAP) len = PAD_CAP;
    size_t s = (size_t)b * PAD_CAP;
    size_t e = s + len;
    float acc = accumulate ? out[(size_t)row * DIM + lane] : 0.f;
    size_t k = s;
    for (; k + 8 <= e; k += 8) {
        uint r0 = rec[k],   r1 = rec[k+1], r2 = rec[k+2], r3 = rec[k+3];
        uint r4 = rec[k+4], r5 = rec[k+5], r6 = rec[k+6], r7 = rec[k+7];
        ushort b0 = emb16[(size_t)(r0 >> 15) * DIM + lane];
        ushort b1 = emb16[(size_t)(r1 >> 15) * DIM + lane];
        ushort b2 = emb16[(size_t)(r2 >> 15) * DIM + lane];
        ushort b3 = emb16[(size_t)(r3 >> 15) * DIM + lane];
        ushort b4 = emb16[(size_t)(r4 >> 15) * DIM + lane];
        ushort b5 = emb16[(size_t)(r5 >> 15) * DIM + lane];
        ushort b6 = emb16[(size_t)(r6 >> 15) * DIM + lane];
        ushort b7 = emb16[(size_t)(r7 >> 15) * DIM + lane];
        acc += (float)(r0 & 0x7FFFu) * W_INV * __uint_as_float((uint)b0 << 16);
        acc += (float)(r1 & 0x7FFFu) * W_INV * __uint_as_float((uint)b1 << 16);
        acc += (float)(r2 & 0x7FFFu) * W_INV * __uint_as_float((uint)b2 << 16);
        acc += (float)(r3 & 0x7FFFu) * W_INV * __uint_as_float((uint)b3 << 16);
        acc += (float)(r4 & 0x7FFFu) * W_INV * __uint_as_float((uint)b4 << 16);
        acc += (float)(r5 & 0x7FFFu) * W_INV * __uint_as_float((uint)b5 << 16);
        acc += (float)(r6 & 0x7FFFu) * W_INV * __uint_as_float((uint)b6 << 16);
        acc += (float)(r7 & 0x7FFFu) * W_INV * __uint_as_float((uint)b7 << 16);
    }
    for (; k + 4 <= e; k += 4) {
        uint r0 = rec[k], r1 = rec[k+1], r2 = rec[k+2], r3 = rec[k+3];
        ushort b0 = emb16[(size_t)(r0 >> 15) * DIM + lane];
        ushort b1 = emb16[(size_t)(r1 >> 15) * DIM + lane];
        ushort b2 = emb16[(size_t)(r2 >> 15) * DIM + lane];
        ushort b3 = emb16[(size_t)(r3 >> 15) * DIM + lane];
        acc += (float)(r0 & 0x7FFFu) * W_INV * __uint_as_float((uint)b0 << 16);
        acc += (float)(r1 & 0x7FFFu) * W_INV * __uint_as_float((uint)b1 << 16);
        acc += (float)(r2 & 0x7FFFu) * W_INV * __uint_as_float((uint)b2 << 16);
        acc += (float)(r3 & 0x7FFFu) * W_INV * __uint_as_float((uint)b3 << 16);
    }
    for (; k < e; ++k) {
        uint r0 = rec[k];
        ushort b0 = emb16[(size_t)(r0 >> 15) * DIM + lane];
        acc += (float)(r0 & 0x7FFFu) * W_INV * __uint_as_float((uint)b0 << 16);
    }
    out[(size_t)row * DIM + lane] = acc;
}

// ======================= exact-CSR fallback tier (round-9) ==================
__global__ __launch_bounds__(256) void rank_both_exact(
    const int4* __restrict__ u4, const int4* __restrict__ i4,
    int* __restrict__ cnt, int n_i, int su_shift, int si_shift,
    int4* __restrict__ rank_i, int4* __restrict__ rank_u)
{
    int t = blockIdx.x * blockDim.x + threadIdx.x;
    if (t >= NUM_EDGES / 4) return;
    int4 u = u4[t];
    int4 i = i4[t];
    int4 ri, ru;
    ri.x = atomicAdd(&cnt[(u.x >> su_shift) * NUM_ITEMS + i.x], 1);
    ri.y = atomicAdd(&cnt[(u.y >> su_shift) * NUM_ITEMS + i.y], 1);
    ri.z = atomicAdd(&cnt[(u.z >> su_shift) * NUM_ITEMS + i.z], 1);
    ri.w = atomicAdd(&cnt[(u.w >> su_shift) * NUM_ITEMS + i.w], 1);
    ru.x = atomicAdd(&cnt[n_i + (i.x >> si_shift) * NUM_USERS + u.x], 1);
    ru.y = atomicAdd(&cnt[n_i + (i.y >> si_shift) * NUM_USERS + u.y], 1);
    ru.z = atomicAdd(&cnt[n_i + (i.z >> si_shift) * NUM_USERS + u.z], 1);
    ru.w = atomicAdd(&cnt[n_i + (i.w >> si_shift) * NUM_USERS + u.w], 1);
    rank_i[t] = ri;
    rank_u[t] = ru;
}

__global__ __launch_bounds__(SCAN_THREADS) void scan_block_sums(
    const int* __restrict__ cnt, int* __restrict__ bsum, int n, int chunk)
{
    int b = blockIdx.x, t = threadIdx.x;
    int base = b * chunk;
    int end  = base + chunk < n ? base + chunk : n;
    int tch  = (chunk + SCAN_THREADS - 1) / SCAN_THREADS;
    int s = base + t * tch;
    int e = s + tch < end ? s + tch : end;
    int local = 0;
    for (int i = s; i < e; ++i) local += cnt[i];
    __shared__ int sm[SCAN_THREADS];
    sm[t] = local;
    __syncthreads();
    for (int o = SCAN_THREADS / 2; o > 0; o >>= 1) {
        if (t < o) sm[t] += sm[t + o];
        __syncthreads();
    }
    if (t == 0) bsum[b] = sm[0];
}

__global__ __launch_bounds__(SCAN_NB) void scan_block_offsets(
    const int* __restrict__ bsum, int* __restrict__ boff,
    int* __restrict__ off_end)
{
    int t = threadIdx.x;
    __shared__ int sm[SCAN_NB];
    int v = bsum[t];
    sm[t] = v;
    __syncthreads();
    for (int o = 1; o < SCAN_NB; o <<= 1) {
        int x = (t >= o) ? sm[t - o] : 0;
        __syncthreads();
        sm[t] += x;
        __syncthreads();
    }
    boff[t] = sm[t] - v;
    if (t == SCAN_NB - 1) *off_end = sm[SCAN_NB - 1];
}

__global__ __launch_bounds__(SCAN_THREADS) void scan_local(
    int* __restrict__ cnt, const int* __restrict__ boff, int n, int chunk)
{
    int b = blockIdx.x, t = threadIdx.x;
    int base = b * chunk;
    int end  = base + chunk < n ? base + chunk : n;
    int tch  = (chunk + SCAN_THREADS - 1) / SCAN_THREADS;
    int s = base + t * tch;
    int e = s + tch < end ? s + tch : end;
    int local = 0;
    for (int i = s; i < e; ++i) local += cnt[i];
    __shared__ int sm[SCAN_THREADS];
    sm[t] = local;
    __syncthreads();
    for (int o = 1; o < SCAN_THREADS; o <<= 1) {
        int x = (t >= o) ? sm[t - o] : 0;
        __syncthreads();
        sm[t] += x;
        __syncthreads();
    }
    int run = boff[b] + ((t == 0) ? 0 : sm[t - 1]);
    for (int i = s; i < e; ++i) {
        int c = cnt[i];
        cnt[i] = run;
        run += c;
    }
}

__global__ __launch_bounds__(256) void scatter_all(
    const int4* __restrict__ u4, const int4* __restrict__ i4,
    const float4* __restrict__ n4,
    const int4* __restrict__ rank_i, const int4* __restrict__ rank_u,
    const int* __restrict__ off, int n_i, int su_shift, int si_shift,
    uint* __restrict__ rec)
{
    int t = blockIdx.x * blockDim.x + threadIdx.x;
    if (t >= NUM_EDGES / 4) return;
    int4   u  = u4[t];
    int4   i  = i4[t];
    float4 n  = n4[t];
    int4   ri = rank_i[t];
    int4   ru = rank_u[t];
    uint w0 = (uint)(n.x * W_SCALE + 0.5f); if (w0 > 32767u) w0 = 32767u;
    uint w1 = (uint)(n.y * W_SCALE + 0.5f); if (w1 > 32767u) w1 = 32767u;
    uint w2 = (uint)(n.z * W_SCALE + 0.5f); if (w2 > 32767u) w2 = 32767u;
    uint w3 = (uint)(n.w * W_SCALE + 0.5f); if (w3 > 32767u) w3 = 32767u;
    int pi0 = off[(u.x >> su_shift) * NUM_ITEMS + i.x] + ri.x;
    int pi1 = off[(u.y >> su_shift) * NUM_ITEMS + i.y] + ri.y;
    int pi2 = off[(u.z >> su_shift) * NUM_ITEMS + i.z] + ri.z;
    int pi3 = off[(u.w >> su_shift) * NUM_ITEMS + i.w] + ri.w;
    int pu0 = off[n_i + (i.x >> si_shift) * NUM_USERS + u.x] + ru.x;
    int pu1 = off[n_i + (i.y >> si_shift) * NUM_USERS + u.y] + ru.y;
    int pu2 = off[n_i + (i.z >> si_shift) * NUM_USERS + u.z] + ru.z;
    int pu3 = off[n_i + (i.w >> si_shift) * NUM_USERS + u.w] + ru.w;
    rec[pi0] = ((uint)u.x << 15) | w0;
    rec[pi1] = ((uint)u.y << 15) | w1;
    rec[pi2] = ((uint)u.z << 15) | w2;
    rec[pi3] = ((uint)u.w << 15) | w3;
    rec[pu0] = ((uint)i.x << 15) | w0;
    rec[pu1] = ((uint)i.y << 15) | w1;
    rec[pu2] = ((uint)i.z << 15) | w2;
    rec[pu3] = ((uint)i.w << 15) | w3;
}

__global__ __launch_bounds__(256) void gather_pass(
    const int* __restrict__ off, int bin_base,
    const uint* __restrict__ rec,
    const ushort* __restrict__ emb16,
    float* __restrict__ out, int nrows, int accumulate)
{
    int gid  = blockIdx.x * blockDim.x + threadIdx.x;
    int row  = gid >> 6;
    int lane = gid & 63;
    if (row >= nrows) return;
    int b = bin_base + row;
    int s = off[b];
    int e = off[b + 1];
    float acc = accumulate ? out[(size_t)row * DIM + lane] : 0.f;
    int k = s;
    for (; k + 8 <= e; k += 8) {
        uint r0 = rec[k],   r1 = rec[k+1], r2 = rec[k+2], r3 = rec[k+3];
        uint r4 = rec[k+4], r5 = rec[k+5], r6 = rec[k+6], r7 = rec[k+7];
        ushort b0 = emb16[(size_t)(r0 >> 15) * DIM + lane];
        ushort b1 = emb16[(size_t)(r1 >> 15) * DIM + lane];
        ushort b2 = emb16[(size_t)(r2 >> 15) * DIM + lane];
        ushort b3 = emb16[(size_t)(r3 >> 15) * DIM + lane];
        ushort b4 = emb16[(size_t)(r4 >> 15) * DIM + lane];
        ushort b5 = emb16[(size_t)(r5 >> 15) * DIM + lane];
        ushort b6 = emb16[(size_t)(r6 >> 15) * DIM + lane];
        ushort b7 = emb16[(size_t)(r7 >> 15) * DIM + lane];
        acc += (float)(r0 & 0x7FFFu) * W_INV * __uint_as_float((uint)b0 << 16);
        acc += (float)(r1 & 0x7FFFu) * W_INV * __uint_as_float((uint)b1 << 16);
        acc += (float)(r2 & 0x7FFFu) * W_INV * __uint_as_float((uint)b2 << 16);
        acc += (float)(r3 & 0x7FFFu) * W_INV * __uint_as_float((uint)b3 << 16);
        acc += (float)(r4 & 0x7FFFu) * W_INV * __uint_as_float((uint)b4 << 16);
        acc += (float)(r5 & 0x7FFFu) * W_INV * __uint_as_float((uint)b5 << 16);
        acc += (float)(r6 & 0x7FFFu) * W_INV * __uint_as_float((uint)b6 << 16);
        acc += (float)(r7 & 0x7FFFu) * W_INV * __uint_as_float((uint)b7 << 16);
    }
    for (; k + 4 <= e; k += 4) {
        uint r0 = rec[k], r1 = rec[k+1], r2 = rec[k+2], r3 = rec[k+3];
        ushort b0 = emb16[(size_t)(r0 >> 15) * DIM + lane];
        ushort b1 = emb16[(size_t)(r1 >> 15) * DIM + lane];
        ushort b2 = emb16[(size_t)(r2 >> 15) * DIM + lane];
        ushort b3 = emb16[(size_t)(r3 >> 15) * DIM + lane];
        acc += (float)(r0 & 0x7FFFu) * W_INV * __uint_as_float((uint)b0 << 16);
        acc += (float)(r1 & 0x7FFFu) * W_INV * __uint_as_float((uint)b1 << 16);
        acc += (float)(r2 & 0x7FFFu) * W_INV * __uint_as_float((uint)b2 << 16);
        acc += (float)(r3 & 0x7FFFu) * W_INV * __uint_as_float((uint)b3 << 16);
    }
    for (; k < e; ++k) {
        uint r0 = rec[k];
        ushort b0 = emb16[(size_t)(r0 >> 15) * DIM + lane];
        acc += (float)(r0 & 0x7FFFu) * W_INV * __uint_as_float((uint)b0 << 16);
    }
    out[(size_t)row * DIM + lane] = acc;
}

extern "C" void kernel_launch(void* const* d_in, const int* in_sizes, int n_in,
                              void* d_out, int out_size, void* d_ws, size_t ws_size,
                              hipStream_t stream) {
    const float* user_emb  = (const float*)d_in[0];
    const float* item_emb  = (const float*)d_in[1];
    const float* edge_norm = (const float*)d_in[2];
    const int*   u_idx     = (const int*)d_in[3];
    const int*   i_idx     = (const int*)d_in[4];

    float* agg_users = (float*)d_out;                        // 100000*64
    float* agg_items = agg_users + (size_t)NUM_USERS * DIM;  // 50000*64

    const int un4 = NUM_USERS * DIM / 4;
    const int in4 = NUM_ITEMS * DIM / 4;
    const int eb4 = (NUM_EDGES / 4 + 255) / 256;
    const size_t bf16_bytes = ((size_t)NUM_USERS + NUM_ITEMS) * DIM * sizeof(ushort);

    // ---------- tier 1: padded bins (no scan, no off reads) ----------
    {
        const int n_i = SLICES_U * NUM_ITEMS;       // 350000
        const int n_u = SLICES_I * NUM_USERS;       // 400000
        const int n_total = n_i + n_u;              // 750000
        const size_t cnt_bytes  = (size_t)n_total * sizeof(int);
        const size_t rank_bytes = (size_t)2 * NUM_EDGES * sizeof(ushort);
        const size_t rec_bytes  = (size_t)n_total * PAD_CAP * sizeof(uint);
        const size_t need = cnt_bytes + 64 + rank_bytes + 64 + rec_bytes + 64
                          + bf16_bytes + 256;
        if (ws_size >= need) {
            char* p = (char*)d_ws;
            int*     cnt    = (int*)p;     p += cnt_bytes;
            p = (char*)(((uintptr_t)p + 63) & ~(uintptr_t)63);
            ushort*  rank_i = (ushort*)p;  p += (size_t)NUM_EDGES * sizeof(ushort);
            ushort*  rank_u = (ushort*)p;  p += (size_t)NUM_EDGES * sizeof(ushort);
            p = (char*)(((uintptr_t)p + 63) & ~(uintptr_t)63);
            uint*    rec    = (uint*)p;    p += rec_bytes;
            p = (char*)(((uintptr_t)p + 63) & ~(uintptr_t)63);
            ushort*  ue16   = (ushort*)p;  p += (size_t)NUM_USERS * DIM * sizeof(ushort);
            ushort*  ie16   = (ushort*)p;

            hipMemsetAsync(cnt, 0, cnt_bytes, stream);
            convert_both<<<(un4 + in4 + 255) / 256, 256, 0, stream>>>(
                (const float4*)user_emb, (const float4*)item_emb,
                (ushort4*)ue16, (ushort4*)ie16, un4, in4);
            rank_both<<<eb4, 256, 0, stream>>>(
                (const int4*)u_idx, (const int4*)i_idx, cnt, n_i,
                SLICE_SHIFT, SLICE_SHIFT, (ushort4*)rank_i, (ushort4*)rank_u);
            scatter_pad<<<eb4, 256, 0, stream>>>(
                (const int4*)u_idx, (const int4*)i_idx, (const float4*)edge_norm,
                (const ushort4*)rank_i, (const ushort4*)rank_u,
                n_i, SLICE_SHIFT, SLICE_SHIFT, rec);
            for (int s = 0; s < SLICES_U; ++s) {
                gather_pad<<<((NUM_ITEMS * 64) + 255) / 256, 256, 0, stream>>>(
                    cnt, s * NUM_ITEMS, rec, ue16, agg_items, NUM_ITEMS,
                    s > 0 ? 1 : 0);
            }
            for (int s = 0; s < SLICES_I; ++s) {
                gather_pad<<<((NUM_USERS * 64) + 255) / 256, 256, 0, stream>>>(
                    cnt, n_i + s * NUM_USERS, rec, ie16, agg_users, NUM_USERS,
                    s > 0 ? 1 : 0);
            }
            return;
        }
    }

    // ---------- tier 2/3: exact CSR (round-9 path), sliced or unsliced ------
    {
        const size_t rec_bytes  = (size_t)2 * NUM_EDGES * sizeof(uint);
        const size_t rank_bytes = (size_t)2 * NUM_EDGES * sizeof(int);
        auto need_for = [&](int SU, int SI) -> size_t {
            size_t n_total = (size_t)SU * NUM_ITEMS + (size_t)SI * NUM_USERS;
            size_t off_bytes = (n_total + 1 + 2 * SCAN_NB) * sizeof(int);
            return off_bytes + 64 + rec_bytes + 64 + rank_bytes + 64 + bf16_bytes
                 + 256;
        };
        int SU = 0, SI = 0, su_shift = 17, si_shift = 17;
        if (ws_size >= need_for(SLICES_U, SLICES_I)) {
            SU = SLICES_U; SI = SLICES_I;
            su_shift = SLICE_SHIFT; si_shift = SLICE_SHIFT;
        } else if (ws_size >= need_for(1, 1)) {
            SU = 1; SI = 1;
        }
        if (SU > 0) {
            const int n_i = SU * NUM_ITEMS;
            const int n_u = SI * NUM_USERS;
            const int n_total = n_i + n_u;

            char* p = (char*)d_ws;
            int*   cnt  = (int*)p;   p += (size_t)(n_total + 1) * sizeof(int);
            int*   bsum = (int*)p;   p += (size_t)SCAN_NB * sizeof(int);
            int*   boff = (int*)p;   p += (size_t)SCAN_NB * sizeof(int);
            p = (char*)(((uintptr_t)p + 63) & ~(uintptr_t)63);
            uint*  rec  = (uint*)p;  p += rec_bytes;
            p = (char*)(((uintptr_t)p + 63) & ~(uintptr_t)63);
            int*   rank_i = (int*)p; p += (size_t)NUM_EDGES * sizeof(int);
            int*   rank_u = (int*)p; p += (size_t)NUM_EDGES * sizeof(int);
            p = (char*)(((uintptr_t)p + 63) & ~(uintptr_t)63);
            ushort* ue16 = (ushort*)p; p += (size_t)NUM_USERS * DIM * sizeof(ushort);
            ushort* ie16 = (ushort*)p;

            hipMemsetAsync(cnt, 0, (size_t)(n_total + 1) * sizeof(int), stream);
            convert_both<<<(un4 + in4 + 255) / 256, 256, 0, stream>>>(
                (const float4*)user_emb, (const float4*)item_emb,
                (ushort4*)ue16, (ushort4*)ie16, un4, in4);
            rank_both_exact<<<eb4, 256, 0, stream>>>(
                (const int4*)u_idx, (const int4*)i_idx, cnt, n_i,
                su_shift, si_shift, (int4*)rank_i, (int4*)rank_u);
            const int chunk = (n_total + SCAN_NB - 1) / SCAN_NB;
            scan_block_sums<<<SCAN_NB, SCAN_THREADS, 0, stream>>>(
                cnt, bsum, n_total, chunk);
            scan_block_offsets<<<1, SCAN_NB, 0, stream>>>(bsum, boff, cnt + n_total);
            scan_local<<<SCAN_NB, SCAN_THREADS, 0, stream>>>(
                cnt, boff, n_total, chunk);
            scatter_all<<<eb4, 256, 0, stream>>>(
                (const int4*)u_idx, (const int4*)i_idx, (const float4*)edge_norm,
                (const int4*)rank_i, (const int4*)rank_u,
                cnt, n_i, su_shift, si_shift, rec);
            for (int s = 0; s < SU; ++s) {
                gather_pass<<<((NUM_ITEMS * 64) + 255) / 256, 256, 0, stream>>>(
                    cnt, s * NUM_ITEMS, rec, ue16, agg_items, NUM_ITEMS,
                    s > 0 ? 1 : 0);
            }
            for (int s = 0; s < SI; ++s) {
                gather_pass<<<((NUM_USERS * 64) + 255) / 256, 256, 0, stream>>>(
                    cnt, n_i + s * NUM_USERS, rec, ie16, agg_users, NUM_USERS,
                    s > 0 ? 1 : 0);
            }
            return;
        }
    }

    // ---------- tier 4: scatter-atomic ----------
    hipMemsetAsync(d_out, 0, (size_t)out_size * sizeof(float), stream);
    const long long total_threads = (long long)NUM_EDGES * 64;
    const int blocks = (int)((total_threads + 255) / 256);
    lightgcn_scatter<<<blocks, 256, 0, stream>>>(
        user_emb, item_emb, edge_norm, u_idx, i_idx, agg_users, agg_items);
}